// Round 1
// 1931.570 us; speedup vs baseline: 1.2069x; 1.2069x over previous
//
#include <hip/hip_runtime.h>
#include <cstdint>
#include <cstddef>

// Problem constants
#define SENC  128
#define NSTEPS 159          // 128 encoder + 31 decoder
#define HB16  524288        // shorts per h slot (1 MB), tile-major [r][c][128][16]
#define XSLICE 131072       // shorts per r-slice within a slot: 64 tiles x 2048
#define SLAB_ELEMS 55296    // per-c W_hi slab: 36*3*64*8 shorts
#define FRAG_TOTAL 442368   // 64*36*3*64 fragment slots
#define FS 16               // flag stride in dwords (64B lines)

typedef short  short8  __attribute__((ext_vector_type(8)));
typedef float  floatx4 __attribute__((ext_vector_type(4)));
typedef float  f32x4   __attribute__((ext_vector_type(4)));
typedef int    i32x4   __attribute__((ext_vector_type(4)));
typedef unsigned long long u64;

#define MFMA(a, b, c) __builtin_amdgcn_mfma_f32_16x16x32_bf16((a), (b), (c), 0, 0, 0)

// ---------- raw asm memory ops ----------
// Discipline: asm load results live in singly-assigned named slots (literal
// indices only) consumed only after an explicit WAITVM.
__device__ __forceinline__ i32x4 ld_nc16(const void* p) {      // bypass L1+L2 (coherence point)
    i32x4 r;
    asm volatile("global_load_dwordx4 %0, %1, off sc0 sc1" : "=&v"(r) : "v"(p) : "memory");
    return r;
}
__device__ __forceinline__ i32x4 ld_sc0_16(const void* p) {    // bypass L1, cache in local L2
    i32x4 r;
    asm volatile("global_load_dwordx4 %0, %1, off sc0" : "=&v"(r) : "v"(p) : "memory");
    return r;
}
__device__ __forceinline__ void st_nc8(void* p, u64 v) {       // device-coherent 8B store
    asm volatile("global_store_dwordx2 %0, %1, off sc0 sc1" :: "v"(p), "v"(v) : "memory");
}
#define WAITVM(N) asm volatile("s_waitcnt vmcnt(" #N ")" ::: "memory")
#define WAITLGKM  asm volatile("s_waitcnt lgkmcnt(0)" ::: "memory")

// ---------- agent-scope relaxed atomics ----------
__device__ __forceinline__ unsigned ldu_dev(const unsigned* p) {
    return __hip_atomic_load(p, __ATOMIC_RELAXED, __HIP_MEMORY_SCOPE_AGENT);
}
__device__ __forceinline__ u64 ldq_dev(const u64* p) {
    return __hip_atomic_load(p, __ATOMIC_RELAXED, __HIP_MEMORY_SCOPE_AGENT);
}
__device__ __forceinline__ void stu_dev(unsigned* p, unsigned v) {
    __hip_atomic_store(p, v, __ATOMIC_RELAXED, __HIP_MEMORY_SCOPE_AGENT);
}
__device__ __forceinline__ void stf_dev(float* p, float v) {
    __hip_atomic_store(p, v, __ATOMIC_RELAXED, __HIP_MEMORY_SCOPE_AGENT);
}

// ---------- bf16 helpers (RNE) ----------
__device__ __forceinline__ float bf2f(short s) {
    return __uint_as_float(((unsigned)(unsigned short)s) << 16);
}
__device__ __forceinline__ short f2bf(float f) {
    unsigned u = __float_as_uint(f);
    return (short)((u + 0x7FFFu + ((u >> 16) & 1u)) >> 16);
}
__device__ __forceinline__ void f2pair(float f, short& hi, short& lo) {
    hi = f2bf(f);
    lo = f2bf(f - bf2f(hi));
}

__device__ __forceinline__ float sigm(float x) {
    return 1.0f / (1.0f + __expf(-x));
}
__device__ __forceinline__ float tanh_fast(float x) {
    float cx = fminf(fmaxf(x, -15.0f), 15.0f);
    float e = __expf(2.0f * cx);
    return (e - 1.0f) / (e + 1.0f);
}

// ---------- setup: swizzle W_hi (all K) + Wi_lo (x-part only) into fragment order ----------
__global__ void setup_swizzle(const float* __restrict__ Wi, const float* __restrict__ Wh,
                              short* __restrict__ whi, short* __restrict__ wlo_x) {
    const int idx = blockIdx.x * 256 + threadIdx.x;
    if (idx >= FRAG_TOTAL) return;
    const int l    = idx & 63;
    const int rest = idx >> 6;
    const int t    = rest % 3;
    const int ki   = (rest / 3) % 36;
    const int c    = rest / 108;
    const int nrow = t * 1024 + c * 16 + (l & 15);
    const int kb   = ki * 32 + (l >> 4) * 8;
    short8 vh, vl;
#pragma unroll
    for (int j = 0; j < 8; ++j) {
        const int k = kb + j;
        float w = (k < 128) ? Wi[(size_t)nrow * 128 + k]
                            : Wh[(size_t)nrow * 1024 + (k - 128)];
        short h, lo2;
        f2pair(w, h, lo2);
        vh[j] = h; vl[j] = lo2;
    }
    *(short8*)(whi + (size_t)idx * 8) = vh;
    if (ki < 4) {
        const int xi = ((c * 4 + ki) * 3 + t) * 64 + l;
        *(short8*)(wlo_x + (size_t)xi * 8) = vl;
    }
}

// ---------- region-2 pipeline (depth 16, literal indices only) ----------
#define HISSUE(LDFN, S, KI) hb[S] = LDFN(hrd + ((KI) - 4) * 4096)
#define HCONS(S, KI) do { \
    short8 ah_ = *(short8*)&hb[S]; \
    const int fo_ = (((KI) * 3) * 64 + lane) * 8; \
    short8 b0_ = *(const short8*)(s_whi + fo_); \
    short8 b1_ = *(const short8*)(s_whi + fo_ + 512); \
    short8 b2_ = *(const short8*)(s_whi + fo_ + 1024); \
    aR  = MFMA(ah_, b0_, aR); \
    aZ  = MFMA(ah_, b1_, aZ); \
    aNh = MFMA(ah_, b2_, aNh); \
} while (0)

#define REGION2(LDFN) do { \
    i32x4 hb[16]; \
    HISSUE(LDFN,0,4);   HISSUE(LDFN,1,5);   HISSUE(LDFN,2,6);   HISSUE(LDFN,3,7); \
    HISSUE(LDFN,4,8);   HISSUE(LDFN,5,9);   HISSUE(LDFN,6,10);  HISSUE(LDFN,7,11); \
    HISSUE(LDFN,8,12);  HISSUE(LDFN,9,13);  HISSUE(LDFN,10,14); HISSUE(LDFN,11,15); \
    HISSUE(LDFN,12,16); HISSUE(LDFN,13,17); HISSUE(LDFN,14,18); HISSUE(LDFN,15,19); \
    WAITVM(15); HCONS(0,4);   HISSUE(LDFN,0,20); \
    WAITVM(15); HCONS(1,5);   HISSUE(LDFN,1,21); \
    WAITVM(15); HCONS(2,6);   HISSUE(LDFN,2,22); \
    WAITVM(15); HCONS(3,7);   HISSUE(LDFN,3,23); \
    WAITVM(15); HCONS(4,8);   HISSUE(LDFN,4,24); \
    WAITVM(15); HCONS(5,9);   HISSUE(LDFN,5,25); \
    WAITVM(15); HCONS(6,10);  HISSUE(LDFN,6,26); \
    WAITVM(15); HCONS(7,11);  HISSUE(LDFN,7,27); \
    WAITVM(15); HCONS(8,12);  HISSUE(LDFN,8,28); \
    WAITVM(15); HCONS(9,13);  HISSUE(LDFN,9,29); \
    WAITVM(15); HCONS(10,14); HISSUE(LDFN,10,30); \
    WAITVM(15); HCONS(11,15); HISSUE(LDFN,11,31); \
    WAITVM(15); HCONS(12,16); HISSUE(LDFN,12,32); \
    WAITVM(15); HCONS(13,17); HISSUE(LDFN,13,33); \
    WAITVM(15); HCONS(14,18); HISSUE(LDFN,14,34); \
    WAITVM(15); HCONS(15,19); HISSUE(LDFN,15,35); \
    WAITVM(15); HCONS(0,20); \
    WAITVM(14); HCONS(1,21); \
    WAITVM(13); HCONS(2,22); \
    WAITVM(12); HCONS(3,23); \
    WAITVM(11); HCONS(4,24); \
    WAITVM(10); HCONS(5,25); \
    WAITVM(9);  HCONS(6,26); \
    WAITVM(8);  HCONS(7,27); \
    WAITVM(7);  HCONS(8,28); \
    WAITVM(6);  HCONS(9,29); \
    WAITVM(5);  HCONS(10,30); \
    WAITVM(4);  HCONS(11,31); \
    WAITVM(3);  HCONS(12,32); \
    WAITVM(2);  HCONS(13,33); \
    WAITVM(1);  HCONS(14,34); \
    WAITVM(0);  HCONS(15,35); \
} while (0)

// ---------- region-1 helpers (x part, 3-term hi/lo) ----------
#define R1TRIPLE(KI) do { \
    short8 ah_, al_; \
    _Pragma("unroll") \
    for (int j = 0; j < 8; ++j) { short h2_, l2_; f2pair(f[j], h2_, l2_); ah_[j] = h2_; al_[j] = l2_; } \
    const int fo_ = (((KI) * 3) * 64 + lane) * 8; \
    short8 b0_ = *(const short8*)(s_whi + fo_); \
    short8 b1_ = *(const short8*)(s_whi + fo_ + 512); \
    short8 b2_ = *(const short8*)(s_whi + fo_ + 1024); \
    aR  = MFMA(ah_, b0_, aR);  aR  = MFMA(ah_, L0r[KI], aR);  aR  = MFMA(al_, b0_, aR); \
    aZ  = MFMA(ah_, b1_, aZ);  aZ  = MFMA(ah_, L1r[KI], aZ);  aZ  = MFMA(al_, b1_, aZ); \
    aNi = MFMA(ah_, b2_, aNi); aNi = MFMA(ah_, L2r[KI], aNi); aNi = MFMA(al_, b2_, aNi); \
} while (0)

#define LOADF(KI) do { \
    const float* s_ = feats + ((size_t)brow * 159 + step) * 64 + (KI) * 32 + q * 8; \
    f32x4 a_ = ((const f32x4*)s_)[0], b_ = ((const f32x4*)s_)[1]; \
    _Pragma("unroll") for (int j = 0; j < 4; ++j) { f[j] = a_[j]; f[4 + j] = b_[j]; } \
} while (0)

#define LOADL(KI) do { \
    const float* s_ = labels + ((size_t)brow * 128 + step) * 64 + ((KI) - 2) * 32 + q * 8; \
    f32x4 a_ = ((const f32x4*)s_)[0], b_ = ((const f32x4*)s_)[1]; \
    _Pragma("unroll") for (int j = 0; j < 4; ++j) { f[j] = a_[j]; f[4 + j] = b_[j]; } \
} while (0)

#define LOADP(KI) do { \
    const u64* pp_ = (const u64*)(ps_f32 + (size_t)brow * 64 + ((KI) - 2) * 32 + q * 8); \
    _Pragma("unroll") for (int j = 0; j < 4; ++j) { \
        u64 v_ = ldq_dev(pp_ + j); \
        f[2 * j]     = __uint_as_float((unsigned)v_); \
        f[2 * j + 1] = __uint_as_float((unsigned)(v_ >> 32)); } \
} while (0)

// ---------- main persistent kernel ----------
// Sync design (fresh-slot broadcast):
//  - h(t) lives in its OWN 1 MB slot (never-reused addresses in cached mode), so
//    consumer sc0 loads demand-miss to L3 (coherence point) and the XCD L2
//    multicasts to the ~8 same-r blocks — the old xbuf staging, done by hardware.
//  - One flag round per step: publish (sc0sc1 stores + vmcnt(0)) -> hflag; every
//    block gates region2(t) on all-64 hflag >= t.
//  - WAR on slots (fallback ring-2) is transitive: write h(t+2) gated on
//    all-hflag(t+1), and hflag(t+1) is published only after region2(t) reads.
__global__ __launch_bounds__(512, 2) void gru_main(
    const float* __restrict__ feats, const float* __restrict__ labels,
    const float* __restrict__ bi,    const float* __restrict__ bh,
    const float* __restrict__ Wd,    const float* __restrict__ bd,
    const short* __restrict__ whi_sw, const short* __restrict__ wlo_x,
    short* __restrict__ h16,         float* __restrict__ ps_f32,
    float* __restrict__ out,
    unsigned* __restrict__ hflag,    // [4r][64c] @64B
    unsigned* __restrict__ pflag,    // [4r][64c] @64B
    int nslots)                      // 160 = fresh-per-step (cached), 2 = ring (nc)
{
    __shared__ short s_whi[SLAB_ELEMS];   // 108 KB resident W_hi slab (fragment order)
    __shared__ float s_ps[2048];          // ps-phase h staging (2 rows x 1024)
    __shared__ short s_tr[8][16][18];     // epilogue transpose tiles (padded: bank-safe)

    const int tid  = threadIdx.x;
    const int lane = tid & 63;
    const int wv   = tid >> 6;            // wave 0..7
    const int q    = lane >> 4;
    const int n16  = lane & 15;
    const int c    = blockIdx.x & 63;     // out-group: h-cols [16c, 16c+16)
    const int r    = blockIdx.x >> 6;     // batch-group: rows [128r, 128r+128)
    const bool cached = (nslots > 2);

    // stage W_hi slab
    {
        const f32x4* src = (const f32x4*)(whi_sw + (size_t)c * SLAB_ELEMS);
        f32x4* dst = (f32x4*)s_whi;
        for (int i = tid; i < SLAB_ELEMS / 8; i += 512) dst[i] = src[i];
    }
    __syncthreads();

    const int mbase = r * 128 + wv * 16;  // this wave's 16 batch rows (global)
    const int brow  = mbase + n16;        // A-fragment row for this lane
    const int row_r = c * 16 + n16;       // gate row == D col
    const float bias_r  = bi[row_r] + bh[row_r];
    const float bias_z  = bi[1024 + row_r] + bh[1024 + row_r];
    const float bias_ni = bi[2048 + row_r];
    const float bias_nh = bh[2048 + row_r];

    unsigned* my_hflag = hflag + (r * 64 + c) * FS;
    unsigned* my_pflag = pflag + (r * 64 + c) * FS;
    const unsigned* grp_hfl = hflag + (r * 64) * FS;
    const unsigned* grp_pfl = pflag + (r * 64) * FS;

    // hoist region-1 W_lo fragments (step-invariant): 12 x short8 = 48 VGPRs
    short8 L0r[4], L1r[4], L2r[4];
#pragma unroll
    for (int ki = 0; ki < 4; ++ki) {
        const short* base = wlo_x + (size_t)(((c * 4 + ki) * 3) * 64 + lane) * 8;
        L0r[ki] = *(const short8*)(base);
        L1r[ki] = *(const short8*)(base + 512);
        L2r[ki] = *(const short8*)(base + 1024);
    }

    float hold[4] = {0.f, 0.f, 0.f, 0.f};  // h carried fp32 in-register

    for (int step = 0; step < NSTEPS; ++step) {
        const bool dec = (step >= SENC);
        const unsigned tgt = (unsigned)(step + 1);
        const int rslot = cached ? step       : (step & 1);
        const int wslot = cached ? (step + 1) : ((step + 1) & 1);
        // region2 read base: k = (ki-4)*32 + q*8 -> tile (ki-4)*2+(q>>1), col (q&1)*8
        const short* hrd = h16 + (size_t)rslot * HB16 + (size_t)r * XSLICE
                         + (size_t)(wv * 16 + n16) * 16 + (q & 1) * 8 + (q >> 1) * 2048;
        short* hwr = h16 + (size_t)wslot * HB16 + (size_t)r * XSLICE;

        floatx4 aR  = (floatx4){bias_r,  bias_r,  bias_r,  bias_r};
        floatx4 aZ  = (floatx4){bias_z,  bias_z,  bias_z,  bias_z};
        floatx4 aNi = (floatx4){bias_ni, bias_ni, bias_ni, bias_ni};
        floatx4 aNh = (floatx4){bias_nh, bias_nh, bias_nh, bias_nh};

        // ---- region 1 (x part) hoisted BEFORE the h-wait: off the serial chain ----
        {
            float f[8];
            LOADF(0); R1TRIPLE(0);
            LOADF(1); R1TRIPLE(1);
            if (!dec) {
                LOADL(2); R1TRIPLE(2);
                LOADL(3); R1TRIPLE(3);
            } else {
                // ps(step) published during step-1's ps phase
                if (wv == 0) {
                    while (ldu_dev(grp_pfl + lane * FS) < (unsigned)step)
                        __builtin_amdgcn_s_sleep(1);
                }
                __syncthreads();
                LOADP(2); R1TRIPLE(2);
                LOADP(3); R1TRIPLE(3);
            }
        }

        // ---- h-ready gate + region 2 (h part): direct fresh-slot reads ----
        if (step > 0) {
            if (wv == 0) {
                while (ldu_dev(grp_hfl + lane * FS) < (unsigned)step)
                    __builtin_amdgcn_s_sleep(1);
            }
            __syncthreads();
            if (cached) { REGION2(ld_sc0_16); }   // L2-cached: HW multicast per XCD
            else        { REGION2(ld_nc16); }     // ring-2 fallback: L3 direct
        }

        // ---- epilogue: GRU update; publish own 4KB tile contiguously (tile-major) ----
        {
#pragma unroll
            for (int i = 0; i < 4; ++i) {
                float rr = sigm(aR[i]);
                float zz = sigm(aZ[i]);
                float nn = tanh_fast(aNi[i] + rr * aNh[i]);
                float hv = (1.0f - zz) * nn + zz * hold[i];
                hold[i] = hv;
                s_tr[wv][q * 4 + i][n16] = f2bf(hv);   // D row = q*4+i, col = n16
            }
            WAITLGKM;
            const int rr2 = lane >> 2, seg = lane & 3;
            u64 v = *(const u64*)&s_tr[wv][rr2][seg * 4];
            st_nc8(hwr + (size_t)c * 2048 + (size_t)(wv * 16 + rr2) * 16 + seg * 4, v);
            WAITVM(0);
        }
        __syncthreads();
        if (tid == 0) stu_dev(my_hflag, tgt);          // h(step+1) published

        // ---- ps phase: after encoder (step 127) and every decoder step ----
        if (step >= SENC - 1) {
            const int ot = step - (SENC - 1);          // output time 0..31
            const int prow0 = r * 128 + 2 * c;         // this block's 2 ps rows (global)
            if (wv == 0) {                              // need ALL producers' h rows
                while (ldu_dev(grp_hfl + lane * FS) < tgt)
                    __builtin_amdgcn_s_sleep(1);
            }
            __syncthreads();
            if (tid < 256) {                            // 2 rows x 1024 cols, tile-major gather
                const int rl = tid >> 7, rest = tid & 127;
                const int ct = rest >> 1, half = rest & 1;
                const short* src = hwr + (size_t)ct * 2048
                                 + (size_t)(2 * c + rl) * 16 + half * 8;
                i32x4 v = ld_nc16(src);
                WAITVM(0);
                short8 s = *(short8*)&v;
#pragma unroll
                for (int j = 0; j < 8; ++j)
                    s_ps[rl * 1024 + ct * 16 + half * 8 + j] = bf2f(s[j]);
            }
            __syncthreads();
            const int dot = tid >> 2, quar = tid & 3;
            const int rr2 = dot >> 6, o = dot & 63;
            const float* wrow = Wd + (size_t)o * 1024;
            const float* hrow = s_ps + rr2 * 1024;
            float acc = 0.0f;
#pragma unroll 8
            for (int j = 0; j < 64; ++j) {             // interleaved K-slices: conflict-free
                const int k = j * 16 + quar * 4;
                f32x4 w = *(const f32x4*)(wrow + k);
                f32x4 h4 = *(const f32x4*)(hrow + k);
                acc += h4[0] * w[0] + h4[1] * w[1] + h4[2] * w[2] + h4[3] * w[3];
            }
            acc += __shfl_xor(acc, 1);
            acc += __shfl_xor(acc, 2);
            if (quar == 0) {
                float v = acc + bd[o];
                out[((size_t)ot * 512 + prow0 + rr2) * 64 + o] = v;
                stf_dev(ps_f32 + (size_t)(prow0 + rr2) * 64 + o, v);
            }
            WAITVM(0);
            __syncthreads();
            if (tid == 0) stu_dev(my_pflag, tgt);      // ps(step+1) published
        }
    }
}

extern "C" void kernel_launch(void* const* d_in, const int* in_sizes, int n_in,
                              void* d_out, int out_size, void* d_ws, size_t ws_size,
                              hipStream_t stream) {
    const float* feats  = (const float*)d_in[0];
    const float* labels = (const float*)d_in[1];
    const float* Wi     = (const float*)d_in[2];
    const float* Wh     = (const float*)d_in[3];
    const float* bi     = (const float*)d_in[4];
    const float* bh     = (const float*)d_in[5];
    const float* Wd     = (const float*)d_in[6];
    const float* bd     = (const float*)d_in[7];
    float* out = (float*)d_out;

    char* ws = (char*)d_ws;
    short*    whi_sw = (short*)(ws);                   //  7,077,888 B
    short*    wlo_x  = (short*)(ws + 7077888);         //    786,432 B
    float*    ps_f32 = (float*)(ws + 7864320);         //    131,072 B
    unsigned* hflag  = (unsigned*)(ws + 7995392);      //     16,384 B (4r x 64c x 64B)
    unsigned* pflag  = (unsigned*)(ws + 8011776);      //     16,384 B
    short*    h16    = (short*)(ws + 8388608);         //  nslots x 1 MB h slots

    // cached mode needs slots 0..159 (slot t = h(t)); fallback = 2-slot ring + nc reads
    const size_t need = 8388608ull + 160ull * 1048576ull;  // 176,160,768 B
    int nslots = (ws_size >= need) ? 160 : 2;

    // zero flag state
    hipMemsetAsync(ws + 7995392, 0, 32768, stream);

    setup_swizzle<<<FRAG_TOTAL / 256, 256, 0, stream>>>(Wi, Wh, whi_sw, wlo_x);

    void* args[] = {(void*)&feats, (void*)&labels, (void*)&bi, (void*)&bh,
                    (void*)&Wd, (void*)&bd, (void*)&whi_sw, (void*)&wlo_x,
                    (void*)&h16, (void*)&ps_f32, (void*)&out,
                    (void*)&hflag, (void*)&pflag, (void*)&nslots};
    hipLaunchCooperativeKernel(reinterpret_cast<void*>(gru_main),
                               dim3(256), dim3(512), args, 0, stream);
}